// Round 9
// baseline (216.507 us; speedup 1.0000x reference)
//
#include <hip/hip_runtime.h>
#include <hip/hip_bf16.h>

// Conv2d 3x3 s1 p1, NCHW fp32 -> implicit GEMM, f16 MFMA (absmax 0.0625 verified R4-R6).
// R7: counted-vmcnt deep pipeline (T3+T4) + setprio (T5).
//   conv_mfma5: BM=256ch x BN=128pix x BK=64, 512 thr / 8 waves (wave 64x64),
//   triple-buffered 144KB dynamic LDS, depth-2 prefetch, s_waitcnt vmcnt(6)
//   (never 0) + raw s_barrier per K-step. prep kernels fused into one dispatch.

typedef __attribute__((ext_vector_type(8))) _Float16 half8;
typedef __attribute__((ext_vector_type(4))) float floatx4;

#define NN    32
#define CC    128
#define HH    56
#define WW    56
#define KOUT  256
#define HWs   3136                    // 56*56
#define HP    58                      // padded H/W
#define HPP   (HP * HP)               // 3364
#define XP_SHORTS ((size_t)NN * HPP * CC)    // 13,778,944 f16
#define WT_SHORTS (18 * 16384)               // 18 tiles x 256row x 64c
#define WS_NEED ((XP_SHORTS + WT_SHORTS) * sizeof(short))
#define BUF_HALFS 24576                      // 48KB per buffer (A 32KB | B 16KB)
#define LDS_BYTES (3 * BUF_HALFS * 2)        // 147456 = 144KB

__device__ __forceinline__ void gload_lds16(const void* g, void* l) {
    __builtin_amdgcn_global_load_lds(
        (const __attribute__((address_space(1))) unsigned int*)g,
        (__attribute__((address_space(3))) unsigned int*)l, 16, 0, 0);
}

// ---- fused prep: blocks [0,144) -> W tiles; [144, 144+1856) -> X image -----
// W: [k][c][3][3] fp32 -> Wt[kstep][row 0..255][oct^row&7] f16 (swizzle baked).
// X: [n][c][h][w] fp32 -> Xp[n][hp][wp][c] f16 via LDS transpose, halo fused.
__global__ __launch_bounds__(256) void prep_fused(const float* __restrict__ X,
                                                  const float* __restrict__ Wsrc,
                                                  short* __restrict__ Xp,
                                                  short* __restrict__ Wt) {
    __shared__ float xl[128 * 57];
    const int tid = threadIdx.x;

    if (blockIdx.x < 144) {                  // ---- W part: 144*256 chunks
        const int gid  = blockIdx.x * 256 + tid;   // 0..36863
        const int tile = gid >> 11;                // kstep 0..17
        const int u    = gid & 2047;
        const int r    = u >> 3;                   // row (out-channel) 0..255
        const int o    = u & 7;                    // phys octet
        const int tap  = tile >> 1;
        const int ct   = tile & 1;
        const int c0   = ct * 64 + ((o ^ (r & 7)) << 3);
        _Float16 v[8];
#pragma unroll
        for (int j = 0; j < 8; ++j)
            v[j] = (_Float16)Wsrc[((size_t)r * CC + c0 + j) * 9 + tap];
        *(half8*)&Wt[(size_t)tile * 16384 + u * 8] = *(half8*)v;
        return;
    }

    const int xb = blockIdx.x - 144;         // 0..1855 = n*HP + hp
    const int n  = xb / HP;
    const int hp = xb % HP;
    short* dst = Xp + ((size_t)n * HPP + (size_t)hp * HP) * CC;

    half8 z = {(_Float16)0.f, (_Float16)0.f, (_Float16)0.f, (_Float16)0.f,
               (_Float16)0.f, (_Float16)0.f, (_Float16)0.f, (_Float16)0.f};

    if (hp == 0 || hp == HP - 1) {           // full zero row: 928 half8
#pragma unroll
        for (int it = 0; it < 4; ++it) {
            const int u = it * 256 + tid;
            if (u < 928) *(half8*)&dst[u * 8] = z;
        }
        return;
    }

    const int h = hp - 1;
    const float* src = X + (size_t)n * CC * HWs + h * WW;
#pragma unroll
    for (int i = 0; i < 7; ++i) {
        const int idx = i * 256 + tid;       // [0,1792) = 128c * 14 w4
        const int c   = idx / 14;
        const int w4  = idx - c * 14;
        const floatx4 v = *(const floatx4*)&src[(size_t)c * HWs + w4 * 4];
#pragma unroll
        for (int k = 0; k < 4; ++k) xl[c * 57 + w4 * 4 + k] = v[k];
    }
    __syncthreads();
#pragma unroll
    for (int it = 0; it < 4; ++it) {
        const int u = it * 256 + tid;
        if (u < 896) {
            const int oct = u & 15, w = u >> 4;
            _Float16 v[8];
#pragma unroll
            for (int j = 0; j < 8; ++j)
                v[j] = (_Float16)xl[(oct * 8 + j) * 57 + w];
            *(half8*)&dst[(w + 1) * CC + oct * 8] = *(half8*)v;
        } else if (u < 928) {
            const int q = u - 896;
            const int oct = q & 15;
            const int wpad = (q >> 4) ? (HP - 1) : 0;
            *(half8*)&dst[wpad * CC + oct * 8] = z;
        }
    }
}

// ---- main: 256ch x 128pix, BK=64, 8 waves (wave 64x64), 3-buf counted-vmcnt
__global__ __launch_bounds__(512, 2) void conv_mfma5(
    const short* __restrict__ Xp, const short* __restrict__ Wt,
    const float* __restrict__ bias, float* __restrict__ out) {

    extern __shared__ __align__(16) short smem[];   // 3 x 48KB buffers

    const int tid  = threadIdx.x;
    const int lane = tid & 63;
    const int wid  = tid >> 6;               // 0..7
    const int wr   = wid >> 1;               // ch quarter (64 ch)
    const int wc   = wid & 1;                // pix half (64 pix)
    const int bid  = blockIdx.x;             // 0..783
    const int pblk = (bid & 7) * 98 + (bid >> 3);   // XCD-bijective (784=8*98)

    // B-stage per-lane global bases: 2 chunks, row = wid*16 + i*8 + (lane>>3)
    const int swzoct = (lane & 7) ^ (lane >> 3);    // row&7 == lane>>3
    const short* vsrc[2];
#pragma unroll
    for (int i = 0; i < 2; ++i) {
        const int row = wid * 16 + i * 8 + (lane >> 3);
        const int p   = pblk * 128 + row;
        const int n   = p / HWs;
        const int hw  = p % HWs;
        const int h   = hw / WW;
        const int w   = hw % WW;
        vsrc[i] = Xp + ((size_t)n * HPP + (h + 1) * HP + (w + 1)) * CC + swzoct * 8;
    }

    // A loads: linear copy, src offset == dest offset within tile
    const int aoff = wid * 2048 + lane * 8;

    // issue the 6 loads for K-step kk into buffer bb (halfs offset)
#define STAGE_P0(kk, bb) do {                                                  \
    const short* as_ = Wt + (size_t)(kk) * 16384 + aoff;                       \
    gload_lds16(as_,        &smem[(bb) + aoff]);                               \
    gload_lds16(as_ + 512,  &smem[(bb) + aoff + 512]);                         \
    const int rs_ = (kk) >> 1;                                                 \
    const int tap_ = ((rs_ / 3 - 1) * HP + (rs_ % 3 - 1)) * CC + ((kk) & 1) * 64; \
    gload_lds16(vsrc[0] + tap_, &smem[(bb) + 16384 + wid * 1024 + lane * 8]);  \
} while (0)
#define STAGE_P1(kk, bb) do {                                                  \
    const short* as_ = Wt + (size_t)(kk) * 16384 + aoff;                       \
    gload_lds16(as_ + 1024, &smem[(bb) + aoff + 1024]);                        \
    gload_lds16(as_ + 1536, &smem[(bb) + aoff + 1536]);                        \
    const int rs_ = (kk) >> 1;                                                 \
    const int tap_ = ((rs_ / 3 - 1) * HP + (rs_ % 3 - 1)) * CC + ((kk) & 1) * 64; \
    gload_lds16(vsrc[1] + tap_, &smem[(bb) + 16384 + wid * 1024 + 512 + lane * 8]); \
} while (0)

    floatx4 acc[4][4];
#pragma unroll
    for (int i = 0; i < 4; i++)
#pragma unroll
        for (int j = 0; j < 4; j++) acc[i][j] = (floatx4)(0.0f);

    // prologue: stage t=0 (buf0) and t=1 (buf1); wait t=0's 6; publish
    STAGE_P0(0, 0); STAGE_P1(0, 0);
    STAGE_P0(1, BUF_HALFS); STAGE_P1(1, BUF_HALFS);
    asm volatile("s_waitcnt vmcnt(6)" ::: "memory");
    __builtin_amdgcn_sched_barrier(0);
    __builtin_amdgcn_s_barrier();

    int cur = 0;                             // buffer index of step t
    for (int t = 0; t < 18; ++t) {
        const int cb  = cur * BUF_HALFS;
        const int nxt = (cur + 2 >= 3) ? cur - 1 : cur + 2;  // (cur+2)%3
        const int nb  = nxt * BUF_HALFS;
        const int kk  = (t + 2 < 18) ? t + 2 : 17;           // dummy tail restage

        // ---- phase 0: issue 3 loads for t+2; compute ksub0 of buf[cur]
        STAGE_P0(kk, nb);
        {
            const int koct = (lane >> 4);
            half8 ah[4], bh[4];
#pragma unroll
            for (int mt = 0; mt < 4; ++mt) {
                const int ar = wr * 64 + mt * 16 + (lane & 15);
                ah[mt] = *(const half8*)&smem[cb + ar * 64 + ((koct ^ (ar & 7)) << 3)];
            }
#pragma unroll
            for (int nt = 0; nt < 4; ++nt) {
                const int br = wc * 64 + nt * 16 + (lane & 15);
                bh[nt] = *(const half8*)&smem[cb + 16384 + br * 64 + ((koct ^ (br & 7)) << 3)];
            }
            __builtin_amdgcn_s_setprio(1);
#pragma unroll
            for (int mt = 0; mt < 4; ++mt)
#pragma unroll
                for (int nt = 0; nt < 4; ++nt)
                    acc[mt][nt] = __builtin_amdgcn_mfma_f32_16x16x32_f16(
                        ah[mt], bh[nt], acc[mt][nt], 0, 0, 0);
            __builtin_amdgcn_s_setprio(0);
        }
        __builtin_amdgcn_s_barrier();        // loose lockstep (no drain)

        // ---- phase 1: issue remaining 3 loads for t+2; compute ksub1
        STAGE_P1(kk, nb);
        {
            const int koct = 4 + (lane >> 4);
            half8 ah[4], bh[4];
#pragma unroll
            for (int mt = 0; mt < 4; ++mt) {
                const int ar = wr * 64 + mt * 16 + (lane & 15);
                ah[mt] = *(const half8*)&smem[cb + ar * 64 + ((koct ^ (ar & 7)) << 3)];
            }
#pragma unroll
            for (int nt = 0; nt < 4; ++nt) {
                const int br = wc * 64 + nt * 16 + (lane & 15);
                bh[nt] = *(const half8*)&smem[cb + 16384 + br * 64 + ((koct ^ (br & 7)) << 3)];
            }
            __builtin_amdgcn_s_setprio(1);
#pragma unroll
            for (int mt = 0; mt < 4; ++mt)
#pragma unroll
                for (int nt = 0; nt < 4; ++nt)
                    acc[mt][nt] = __builtin_amdgcn_mfma_f32_16x16x32_f16(
                        ah[mt], bh[nt], acc[mt][nt], 0, 0, 0);
            __builtin_amdgcn_s_setprio(0);
        }

        // end of step: retire t+1's 6 loads (never drain to 0), publish
        asm volatile("s_waitcnt vmcnt(6)" ::: "memory");
        __builtin_amdgcn_sched_barrier(0);
        __builtin_amdgcn_s_barrier();

        cur = (cur + 1 >= 3) ? 0 : cur + 1;
    }
#undef STAGE_P0
#undef STAGE_P1

    // epilogue: C/D col=lane&15 -> pixel, row=(lane>>4)*4+r -> channel
#pragma unroll
    for (int mt = 0; mt < 4; ++mt) {
        const int ch = wr * 64 + mt * 16 + ((lane >> 4) << 2);
#pragma unroll
        for (int nt = 0; nt < 4; ++nt) {
            const int p  = pblk * 128 + wc * 64 + nt * 16 + (lane & 15);
            const int n  = p / HWs;          // 16-pix groups never straddle n
            const int hw = p % HWs;
            float* ob = out + ((size_t)n * KOUT + ch) * HWs + hw;
#pragma unroll
            for (int r = 0; r < 4; ++r)
                ob[(size_t)r * HWs] = acc[mt][nt][r] + bias[ch + r];
        }
    }
}

// ---- fallback: correct naive direct conv -----------------------------------
__global__ __launch_bounds__(256) void conv_naive(const float* __restrict__ X,
                                                  const float* __restrict__ Wt,
                                                  const float* __restrict__ bias,
                                                  float* __restrict__ out) {
    long o = (long)blockIdx.x * 256 + threadIdx.x;
    int w_ = o % WW;
    long t1 = o / WW;
    int h_ = t1 % HH;
    long t2 = t1 / HH;
    int k_ = t2 % KOUT;
    int n_ = (int)(t2 / KOUT);
    float acc = bias[k_];
    for (int c = 0; c < CC; ++c)
        for (int r = 0; r < 3; ++r) {
            int ih = h_ + r - 1;
            if ((unsigned)ih >= 56u) continue;
            for (int s = 0; s < 3; ++s) {
                int iw = w_ + s - 1;
                if ((unsigned)iw >= 56u) continue;
                acc += X[((long)(n_ * CC + c) * HH + ih) * WW + iw] *
                       Wt[((k_ * CC + c) * 3 + r) * 3 + s];
            }
        }
    out[o] = acc;
}

extern "C" void kernel_launch(void* const* d_in, const int* in_sizes, int n_in,
                              void* d_out, int out_size, void* d_ws, size_t ws_size,
                              hipStream_t stream) {
    const float* X    = (const float*)d_in[0];
    const float* Wsrc = (const float*)d_in[1];
    const float* bias = (const float*)d_in[2];
    float* out        = (float*)d_out;

    static hipError_t attr_rc = hipFuncSetAttribute(
        (const void*)conv_mfma5, hipFuncAttributeMaxDynamicSharedMemorySize,
        LDS_BYTES);   // deterministic per-process; same work every call
    hipError_t rc = hipFuncSetAttribute(
        (const void*)conv_mfma5, hipFuncAttributeMaxDynamicSharedMemorySize,
        LDS_BYTES);
    (void)attr_rc;

    if (ws_size >= WS_NEED && rc == hipSuccess) {
        short* Xp = (short*)d_ws;
        short* Wt = Xp + XP_SHORTS;
        prep_fused<<<144 + NN * HP, 256, 0, stream>>>(X, Wsrc, Xp, Wt);
        conv_mfma5<<<784, 512, LDS_BYTES, stream>>>(Xp, Wt, bias, out);
    } else {
        conv_naive<<<100352, 256, 0, stream>>>(X, Wsrc, bias, out);
    }
}